// Round 14
// baseline (157.393 us; speedup 1.0000x reference)
//
#include <hip/hip_runtime.h>
#include <hip/hip_bf16.h>

// B=16384, D=512, F=28, GIN=1053 (padded 1088 = 17*64)
// out[0 .. B*512)      = updated (LayerNorm result), fp32
// out[B*512 .. 2*B*512)= game_context = relu(x@Wproj^T+b), fp32

#define NB 16384
#define GINP 1088

typedef __bf16 bf16x8 __attribute__((ext_vector_type(8)));
typedef float f32x4 __attribute__((ext_vector_type(4)));
typedef unsigned short ushort8 __attribute__((ext_vector_type(8)));

__device__ __forceinline__ void gload_lds16(const void* g, void* l) {
  __builtin_amdgcn_global_load_lds(
      (const __attribute__((address_space(1))) void*)g,
      (__attribute__((address_space(3))) void*)l, 16, 0, 0);
}
// Inline-asm LDS read: opaque to hipcc's vmcnt/lgkmcnt dependency model.
// Caller must s_waitcnt lgkmcnt(0) + sched_barrier(0) before consuming.
__device__ __forceinline__ bf16x8 ds_read128(const unsigned short* l) {
  f32x4 r;
  asm volatile("ds_read_b128 %0, %1"
               : "=v"(r)
               : "v"((const __attribute__((address_space(3))) void*)l));
  bf16x8 out;
  __builtin_memcpy(&out, &r, 16);
  return out;
}
__device__ __forceinline__ float sigmoidf_(float x) { return 1.0f / (1.0f + expf(-x)); }
__device__ __forceinline__ float bf2f(unsigned short u) {
  unsigned int x = ((unsigned int)u) << 16;
  float f; __builtin_memcpy(&f, &x, 4); return f;
}

// ---------------- merged prep: X bf16 [NB][1088] + weight casts (round-11) ----------------
#define PREP_X_BLOCKS ((NB * 136 + 255) / 256)
__global__ __launch_bounds__(256) void prep_all(
    const float* __restrict__ team, const float* __restrict__ opp,
    const float* __restrict__ gf, const float* __restrict__ won,
    const float* __restrict__ Wproj, const float* __restrict__ Wih,
    const float* __restrict__ Whh, const float* __restrict__ Wimp1,
    const float* __restrict__ bih, const float* __restrict__ bhh,
    __hip_bfloat16* __restrict__ X,
    __hip_bfloat16* __restrict__ Wpb, __hip_bfloat16* __restrict__ Wrz,
    __hip_bfloat16* __restrict__ Wn, __hip_bfloat16* __restrict__ Wimp1b,
    float* __restrict__ bcat) {
  if (blockIdx.x < PREP_X_BLOCKS) {
    long idx = (long)blockIdx.x * 256 + threadIdx.x;  // NB*136 slots of 8 cols
    if (idx >= (long)NB * 136) return;
    const int r = (int)(idx / 136);
    const int c8 = (int)(idx % 136) * 8;
    float v[8];
    if (c8 < 512) {
      float4 a = *(const float4*)&team[(size_t)r * 512 + c8];
      float4 b = *(const float4*)&team[(size_t)r * 512 + c8 + 4];
      v[0]=a.x; v[1]=a.y; v[2]=a.z; v[3]=a.w; v[4]=b.x; v[5]=b.y; v[6]=b.z; v[7]=b.w;
    } else if (c8 < 1024) {
      float4 a = *(const float4*)&opp[(size_t)r * 512 + (c8 - 512)];
      float4 b = *(const float4*)&opp[(size_t)r * 512 + (c8 - 512) + 4];
      v[0]=a.x; v[1]=a.y; v[2]=a.z; v[3]=a.w; v[4]=b.x; v[5]=b.y; v[6]=b.z; v[7]=b.w;
    } else if (c8 < 1048) {
      const int g0 = c8 - 1024;
#pragma unroll
      for (int e = 0; e < 8; ++e) v[e] = gf[(size_t)r * 28 + g0 + e];
    } else if (c8 == 1048) {
      v[0] = gf[(size_t)r * 28 + 24]; v[1] = gf[(size_t)r * 28 + 25];
      v[2] = gf[(size_t)r * 28 + 26]; v[3] = gf[(size_t)r * 28 + 27];
      v[4] = won[r]; v[5] = 0.f; v[6] = 0.f; v[7] = 0.f;
    } else {
#pragma unroll
      for (int e = 0; e < 8; ++e) v[e] = 0.f;
    }
    __hip_bfloat16 h[8];
#pragma unroll
    for (int e = 0; e < 8; ++e) h[e] = __float2bfloat16(v[e]);
    *(uint4*)&X[(size_t)r * GINP + c8] = *(const uint4*)h;
    return;
  }
  long idx = (long)(blockIdx.x - PREP_X_BLOCKS) * 256 + threadIdx.x;
  if (idx < 512L * 1088) {
    int r = (int)(idx / 1088), c = (int)(idx % 1088);
    Wpb[idx] = __float2bfloat16(c < 1053 ? Wproj[(size_t)r * 1053 + c] : 0.f);
    return;
  }
  idx -= 512L * 1088;
  if (idx < 1024L * 1024) {
    int q = (int)(idx >> 10), c = (int)(idx & 1023);
    float v = (c < 512) ? Wih[(size_t)q * 512 + c] : Whh[(size_t)q * 512 + (c - 512)];
    Wrz[idx] = __float2bfloat16(v);
    return;
  }
  idx -= 1024L * 1024;
  if (idx < 1024L * 512) {
    int q = (int)(idx / 512), c = (int)(idx % 512);
    float v = (q < 512) ? Wih[(size_t)(1024 + q) * 512 + c]
                        : Whh[(size_t)(1024 + q - 512) * 512 + c];
    Wn[idx] = __float2bfloat16(v);
    return;
  }
  idx -= 1024L * 512;
  if (idx < 128L * 512) { Wimp1b[idx] = __float2bfloat16(Wimp1[idx]); return; }
  idx -= 128L * 512;
  if (idx < 2048) {
    int j = (int)idx;
    float v;
    if (j < 1024) v = bih[j] + bhh[j];
    else if (j < 1536) v = bih[j];
    else v = bhh[j - 512];
    bcat[j] = v;
  }
}

// ---------------- projection GEMM: 128x128 tile, ring-2, 2 blocks/CU (round-9/11) --------
__global__ __launch_bounds__(256, 2) void gemm_proj(
    const __hip_bfloat16* __restrict__ A0,
    const __hip_bfloat16* __restrict__ W0, const float* __restrict__ bias,
    float* __restrict__ Cf, __hip_bfloat16* __restrict__ Cb) {
  __shared__ __align__(16) unsigned short ldsA[2 * 128 * 64];
  __shared__ __align__(16) unsigned short ldsB[2 * 128 * 64];

  const int tid = threadIdx.x;
  const int wid = tid >> 6, lane = tid & 63;
  const int wr = wid >> 1, wc = wid & 1;
  const int fl = lane & 15, kh = lane >> 4;
  const int prow_b = tid >> 3;
  const int gp = tid & 7;

  int bid = blockIdx.x;
  { const int cpx = gridDim.x >> 3; bid = (bid & 7) * cpx + (bid >> 3); }
  const int tm = bid >> 2, tn = bid & 3;
  const int m0 = tm * 128;
  const int NT = 17;

  const __hip_bfloat16* Wp = W0 + (size_t)tn * 128 * GINP;
  const float* bp = bias + tn * 128;

  auto stage = [&](int s) {
    const int k0 = s * 64;
    unsigned short* la = &ldsA[(s & 1) * 8192];
    unsigned short* lb = &ldsB[(s & 1) * 8192];
#pragma unroll
    for (int i = 0; i < 4; ++i) {
      const int row = i * 32 + prow_b;
      const int gl = gp ^ (row & 7);
      gload_lds16(A0 + (size_t)(m0 + row) * GINP + k0 + gl * 8,
                  la + (i * 32 + wid * 8) * 64);
      gload_lds16(Wp + (size_t)row * GINP + k0 + gl * 8,
                  lb + (i * 32 + wid * 8) * 64);
    }
  };

  f32x4 acc[4][4];
#pragma unroll
  for (int m = 0; m < 4; ++m)
#pragma unroll
    for (int n = 0; n < 4; ++n) acc[m][n] = (f32x4){0.f, 0.f, 0.f, 0.f};

  stage(0);

  for (int t = 0; t < NT; ++t) {
    const int sl = (t & 1) * 8192;
    asm volatile("s_waitcnt vmcnt(0)" ::: "memory");
    __builtin_amdgcn_s_barrier();
    if (t + 1 < NT) stage(t + 1);

    bf16x8 af[2][4], bfr[2][4];
#pragma unroll
    for (int kk = 0; kk < 2; ++kk) {
#pragma unroll
      for (int m = 0; m < 4; ++m) {
        const int r = wr * 64 + m * 16 + fl;
        const int g = (kk * 4 + kh) ^ (r & 7);
        af[kk][m] = ds_read128(&ldsA[sl + r * 64 + g * 8]);
      }
#pragma unroll
      for (int n = 0; n < 4; ++n) {
        const int r = wc * 64 + n * 16 + fl;
        const int g = (kk * 4 + kh) ^ (r & 7);
        bfr[kk][n] = ds_read128(&ldsB[sl + r * 64 + g * 8]);
      }
    }
    asm volatile("s_waitcnt lgkmcnt(0)" ::: "memory");
    __builtin_amdgcn_sched_barrier(0);
    __builtin_amdgcn_s_setprio(1);
#pragma unroll
    for (int kk = 0; kk < 2; ++kk)
#pragma unroll
      for (int m = 0; m < 4; ++m)
#pragma unroll
        for (int n = 0; n < 4; ++n)
          acc[m][n] = __builtin_amdgcn_mfma_f32_16x16x32_bf16(af[kk][m], bfr[kk][n], acc[m][n], 0, 0, 0);
    __builtin_amdgcn_s_setprio(0);
  }

  // Epilogue (verified): C/D map col = lane&15, row = (lane>>4)*4 + j
#pragma unroll
  for (int m = 0; m < 4; ++m)
#pragma unroll
    for (int n = 0; n < 4; ++n)
#pragma unroll
      for (int j = 0; j < 4; ++j) {
        const int lrow = wr * 64 + m * 16 + kh * 4 + j;
        const int lcol = wc * 64 + n * 16 + fl;
        const size_t grow = (size_t)(m0 + lrow);
        float v = acc[m][n][j] + bp[lcol];
        v = fmaxf(v, 0.f);
        Cf[grow * 512 + tn * 128 + lcol] = v;
        Cb[grow * 512 + tn * 128 + lcol] = __float2bfloat16(v);
      }
}

// ---------------- gates GEMM (ring-3 BK=32 counted vmcnt) + importance tail ----------------
// blocks 0..2047: gates 128x128, BK=32, 3 LDS slots (48KB), 4 waves (2x2, 64x64 each).
//   Per step t: vmcnt(4) [drains stage(t), issued 2 steps earlier -> L2 latency hidden;
//   stage(t+1)'s 4 loads stay in flight] -> barrier -> issue stage(t+2) -> 8 asm
//   ds_reads -> lgkmcnt(0) -> 16 MFMA. Write-safety: stage(t+2) targets slot(t-1),
//   whose reads were retired at t-1's lgkmcnt(0), before every wave passed barrier(t).
//   Swizzle (r13-verified): 64B rows, granule gl = gp ^ ((row>>1)&3) on source, same
//   XOR on read (involution; 2-way bank alias = free).
// blocks 2048..2303: importance (round-11 verified path).
// tn<8: K=1024 concat-A (s<16: P, s>=16: team=Xb), W=Wrz rows tn*128, NT=32;
// tn 8-11: A=P, W=Wn[(tn-8)*128..] (i_n), NT=16; tn 12-15: A=Xb, W=Wn[512+..] (h_n).
__global__ __launch_bounds__(256, 2) void gates_imp(
    const __hip_bfloat16* __restrict__ Pm, const __hip_bfloat16* __restrict__ Xb,
    const __hip_bfloat16* __restrict__ Wrz, const __hip_bfloat16* __restrict__ Wn,
    const float* __restrict__ bcat, __hip_bfloat16* __restrict__ gg,
    const __hip_bfloat16* __restrict__ Wimp1b, const float* __restrict__ b1,
    const float* __restrict__ w2, const float* __restrict__ b2,
    float* __restrict__ imp) {
  __shared__ __align__(16) unsigned short lds[24576];  // 48KB

  const int tid = threadIdx.x;
  const int wid = tid >> 6, lane = tid & 63;
  const int fl = lane & 15, kh = lane >> 4;

  if (blockIdx.x >= 2048) {
    // ---------- importance path (round-11 verified) ----------
    unsigned short* ldsA = lds;            // 64x64
    unsigned short* ldsB = lds + 4096;     // 128x64
    float* sdot = (float*)(lds + 12288);
    const int wr = wid >> 1, wc = wid & 1;
    const int srow = lane >> 3, scol = (lane & 7) * 8;
    const int m0 = (blockIdx.x - 2048) * 64;

    if (tid < 64) sdot[tid] = 0.f;

    f32x4 acc[2][4];
#pragma unroll
    for (int m = 0; m < 2; ++m)
#pragma unroll
      for (int n = 0; n < 4; ++n) acc[m][n] = (f32x4){0.f, 0.f, 0.f, 0.f};

    for (int kt = 0; kt < 8; ++kt) {
      const int k0 = kt * 64;
#pragma unroll
      for (int c = 0; c < 2; ++c) {
        const int rgrp = c * 4 + wid;
        const int row = rgrp * 8 + srow;
        gload_lds16(Pm + (size_t)(m0 + row) * 512 + k0 + scol, (char*)ldsA + rgrp * 1024);
      }
#pragma unroll
      for (int c = 0; c < 4; ++c) {
        const int rgrp = c * 4 + wid;
        const int row = rgrp * 8 + srow;
        gload_lds16(Wimp1b + (size_t)row * 512 + k0 + scol, (char*)ldsB + rgrp * 1024);
      }
      __syncthreads();
#pragma unroll
      for (int kk = 0; kk < 2; ++kk) {
        bf16x8 af[2], bfr[4];
#pragma unroll
        for (int m = 0; m < 2; ++m)
          af[m] = *(const bf16x8*)&ldsA[(wr * 32 + m * 16 + fl) * 64 + kk * 32 + kh * 8];
#pragma unroll
        for (int n = 0; n < 4; ++n)
          bfr[n] = *(const bf16x8*)&ldsB[(wc * 64 + n * 16 + fl) * 64 + kk * 32 + kh * 8];
#pragma unroll
        for (int m = 0; m < 2; ++m)
#pragma unroll
          for (int n = 0; n < 4; ++n)
            acc[m][n] = __builtin_amdgcn_mfma_f32_16x16x32_bf16(af[m], bfr[n], acc[m][n], 0, 0, 0);
      }
      __syncthreads();
    }
#pragma unroll
    for (int m = 0; m < 2; ++m)
#pragma unroll
      for (int j = 0; j < 4; ++j) {
        float p = 0.f;
#pragma unroll
        for (int n = 0; n < 4; ++n) {
          const int lcol = wc * 64 + n * 16 + fl;
          const float v = fmaxf(acc[m][n][j] + b1[lcol], 0.f);
          p += v * w2[lcol];
        }
        atomicAdd(&sdot[wr * 32 + m * 16 + kh * 4 + j], p);
      }
    __syncthreads();
    if (tid < 64) imp[m0 + tid] = sigmoidf_(sdot[tid] + b2[0]);
    return;
  }

  // ---------- gates path: ring-3, BK=32 ----------
  unsigned short* ldsA = lds;            // 3 slots x 128x32 = 12288 elems
  unsigned short* ldsB = lds + 12288;    // 3 slots x 128x32
  const int wr = wid >> 1, wc = wid & 1;
  const int srow_q = tid >> 2;           // 0..63
  const int gp = tid & 3;

  int bid = blockIdx.x;
  bid = (bid & 7) * 256 + (bid >> 3);    // XCD swizzle over 2048 blocks
  const int tm = bid >> 4, tn = bid & 15;
  const int m0 = tm * 128;

  const __hip_bfloat16* Wp; int ldw, NT;
  if (tn < 8) { Wp = Wrz + (size_t)tn * 128 * 1024; ldw = 1024; NT = 32; }
  else        { Wp = Wn + (size_t)(tn - 8) * 128 * 512; ldw = 512; NT = 16; }
  const float* bp = bcat + tn * 128;

  auto stage = [&](int s) {
    const int kW = s * 32;
    const __hip_bfloat16* Ap; int lda; int kA;
    if (tn < 8) {
      if (s < 16) { Ap = Pm; lda = 512; kA = s * 32; }
      else        { Ap = Xb; lda = GINP; kA = (s - 16) * 32; }
    } else if (tn < 12) { Ap = Pm; lda = 512; kA = s * 32; }
    else                { Ap = Xb; lda = GINP; kA = s * 32; }
    unsigned short* la = &ldsA[(s % 3) * 4096];
    unsigned short* lb = &ldsB[(s % 3) * 4096];
#pragma unroll
    for (int i = 0; i < 2; ++i) {        // rows i*64 .. i*64+63 of [128][32]
      const int row = i * 64 + srow_q;
      const int gl = gp ^ ((row >> 1) & 3);
      gload_lds16(Ap + (size_t)(m0 + row) * lda + kA + gl * 8,
                  la + i * 2048 + wid * 512);
      gload_lds16(Wp + (size_t)row * ldw + kW + gl * 8,
                  lb + i * 2048 + wid * 512);
    }
  };

  f32x4 acc[4][4];
#pragma unroll
  for (int m = 0; m < 4; ++m)
#pragma unroll
    for (int n = 0; n < 4; ++n) acc[m][n] = (f32x4){0.f, 0.f, 0.f, 0.f};

  stage(0); stage(1);

  for (int t = 0; t < NT; ++t) {
    const int sl = (t % 3) * 4096;
    if (t + 1 < NT) { asm volatile("s_waitcnt vmcnt(4)" ::: "memory"); }
    else            { asm volatile("s_waitcnt vmcnt(0)" ::: "memory"); }
    __builtin_amdgcn_s_barrier();
    if (t + 2 < NT) stage(t + 2);

    bf16x8 af[4], bfr[4];
#pragma unroll
    for (int m = 0; m < 4; ++m) {
      const int r = wr * 64 + m * 16 + fl;
      const int g = kh ^ ((r >> 1) & 3);
      af[m] = ds_read128(&ldsA[sl + r * 32 + g * 8]);
    }
#pragma unroll
    for (int n = 0; n < 4; ++n) {
      const int r = wc * 64 + n * 16 + fl;
      const int g = kh ^ ((r >> 1) & 3);
      bfr[n] = ds_read128(&ldsB[sl + r * 32 + g * 8]);
    }
    asm volatile("s_waitcnt lgkmcnt(0)" ::: "memory");
    __builtin_amdgcn_sched_barrier(0);
    __builtin_amdgcn_s_setprio(1);
#pragma unroll
    for (int m = 0; m < 4; ++m)
#pragma unroll
      for (int n = 0; n < 4; ++n)
        acc[m][n] = __builtin_amdgcn_mfma_f32_16x16x32_bf16(af[m], bfr[n], acc[m][n], 0, 0, 0);
    __builtin_amdgcn_s_setprio(0);
  }

  // Epilogue (round-9/11 verified): C/D map col = lane&15, row = (lane>>4)*4 + j
#pragma unroll
  for (int m = 0; m < 4; ++m)
#pragma unroll
    for (int n = 0; n < 4; ++n)
#pragma unroll
      for (int j = 0; j < 4; ++j) {
        const int lrow = wr * 64 + m * 16 + kh * 4 + j;
        const int lcol = wc * 64 + n * 16 + fl;
        gg[(size_t)(m0 + lrow) * 2048 + tn * 128 + lcol] =
            __float2bfloat16(acc[m][n][j] + bp[lcol]);
      }
}

// ---------------- fused GRU + blend + LayerNorm (vectorized, 1 wave/row) ----------------
// gg [NB][2048]: [s_r | s_z | i_n | h_n]
__global__ __launch_bounds__(256) void fuse_final2(
    const float* __restrict__ team, const __hip_bfloat16* __restrict__ gg,
    const float* __restrict__ imp, const float* __restrict__ gamma,
    const float* __restrict__ beta, float* __restrict__ out) {
  const int row = blockIdx.x * 4 + (threadIdx.x >> 6);
  const int lane = threadIdx.x & 63;
  const size_t gb = (size_t)row * 2048 + lane * 8;
  ushort8 sr = *(const ushort8*)&gg[gb];
  ushort8 szv = *(const ushort8*)&gg[gb + 512];
  ushort8 inn = *(const ushort8*)&gg[gb + 1024];
  ushort8 hnn = *(const ushort8*)&gg[gb + 1536];
  float4 t0 = *(const float4*)&team[(size_t)row * 512 + lane * 8];
  float4 t1 = *(const float4*)&team[(size_t)row * 512 + lane * 8 + 4];
  const float im = imp[row];
  float tv[8] = {t0.x, t0.y, t0.z, t0.w, t1.x, t1.y, t1.z, t1.w};
  float u[8];
  float s = 0.f, ss = 0.f;
#pragma unroll
  for (int e = 0; e < 8; ++e) {
    const float rg = sigmoidf_(bf2f(sr[e]));
    const float zg = sigmoidf_(bf2f(szv[e]));
    const float ng = tanhf(bf2f(inn[e]) + rg * bf2f(hnn[e]));
    const float ne = (1.f - zg) * ng + zg * tv[e];
    const float uu = tv[e] + im * (ne - tv[e]);
    u[e] = uu; s += uu; ss += uu * uu;
  }
#pragma unroll
  for (int off = 32; off; off >>= 1) {
    s += __shfl_down(s, off);
    ss += __shfl_down(ss, off);
  }
  s = __shfl(s, 0); ss = __shfl(ss, 0);
  const float mu = s * (1.f / 512.f);
  const float inv = rsqrtf(ss * (1.f / 512.f) - mu * mu + 1e-5f);
  float4 g0 = *(const float4*)&gamma[lane * 8], g1 = *(const float4*)&gamma[lane * 8 + 4];
  float4 b0 = *(const float4*)&beta[lane * 8], b1 = *(const float4*)&beta[lane * 8 + 4];
  float gv[8] = {g0.x, g0.y, g0.z, g0.w, g1.x, g1.y, g1.z, g1.w};
  float bv[8] = {b0.x, b0.y, b0.z, b0.w, b1.x, b1.y, b1.z, b1.w};
  float4 o0, o1;
  o0.x = gv[0] * (u[0] - mu) * inv + bv[0];
  o0.y = gv[1] * (u[1] - mu) * inv + bv[1];
  o0.z = gv[2] * (u[2] - mu) * inv + bv[2];
  o0.w = gv[3] * (u[3] - mu) * inv + bv[3];
  o1.x = gv[4] * (u[4] - mu) * inv + bv[4];
  o1.y = gv[5] * (u[5] - mu) * inv + bv[5];
  o1.z = gv[6] * (u[6] - mu) * inv + bv[6];
  o1.w = gv[7] * (u[7] - mu) * inv + bv[7];
  *(float4*)&out[(size_t)row * 512 + lane * 8] = o0;
  *(float4*)&out[(size_t)row * 512 + lane * 8 + 4] = o1;
}

// ---------------- launch ----------------
extern "C" void kernel_launch(void* const* d_in, const int* in_sizes, int n_in,
                              void* d_out, int out_size, void* d_ws, size_t ws_size,
                              hipStream_t stream) {
  const float* team   = (const float*)d_in[0];
  const float* opp    = (const float*)d_in[1];
  const float* gf     = (const float*)d_in[2];
  const float* won    = (const float*)d_in[3];
  const float* W_proj = (const float*)d_in[4];
  const float* b_proj = (const float*)d_in[5];
  const float* W_ih   = (const float*)d_in[6];
  const float* b_ih   = (const float*)d_in[7];
  const float* W_hh   = (const float*)d_in[8];
  const float* b_hh   = (const float*)d_in[9];
  const float* gamma  = (const float*)d_in[10];
  const float* beta   = (const float*)d_in[11];
  const float* W_imp1 = (const float*)d_in[12];
  const float* b_imp1 = (const float*)d_in[13];
  const float* W_imp2 = (const float*)d_in[14];
  const float* b_imp2 = (const float*)d_in[15];

  char* ws = (char*)d_ws;
  size_t o = 0;
  __hip_bfloat16* Xbf    = (__hip_bfloat16*)(ws + o); o += (size_t)NB * GINP * 2;
  __hip_bfloat16* Wpb    = (__hip_bfloat16*)(ws + o); o += (size_t)512 * GINP * 2;
  __hip_bfloat16* Wrz    = (__hip_bfloat16*)(ws + o); o += (size_t)1024 * 1024 * 2;
  __hip_bfloat16* Wn     = (__hip_bfloat16*)(ws + o); o += (size_t)1024 * 512 * 2;
  __hip_bfloat16* Wimp1b = (__hip_bfloat16*)(ws + o); o += (size_t)128 * 512 * 2;
  float*          bcat   = (float*)(ws + o);          o += (size_t)2048 * 4;
  __hip_bfloat16* Pbf    = (__hip_bfloat16*)(ws + o); o += (size_t)NB * 512 * 2;
  float*          imp    = (float*)(ws + o);          o += (size_t)NB * 4;
  __hip_bfloat16* gg     = (__hip_bfloat16*)(ws + o); o += (size_t)NB * 2048 * 2;

  float* out_updated = (float*)d_out;
  float* out_ctx     = (float*)d_out + (size_t)NB * 512;

  {
    const long wtotal = 512L * 1088 + 1024L * 1024 + 1024L * 512 + 128L * 512 + 2048;
    const int wblocks = (int)((wtotal + 255) / 256);
    prep_all<<<PREP_X_BLOCKS + wblocks, 256, 0, stream>>>(
        team, opp, gf, won, W_proj, W_ih, W_hh, W_imp1, b_ih, b_hh,
        Xbf, Wpb, Wrz, Wn, Wimp1b, bcat);
  }
  // projected = relu(X @ Wpb^T + b_proj): 128x4 = 512 blocks
  gemm_proj<<<512, 256, 0, stream>>>(Xbf, Wpb, b_proj, out_ctx, Pbf);
  // gates (2048 blocks, ring-3 BK32) + importance (256 tail blocks)
  gates_imp<<<2304, 256, 0, stream>>>(Pbf, Xbf, Wrz, Wn, bcat, gg,
                                      Wimp1b, b_imp1, W_imp2, b_imp2, imp);
  fuse_final2<<<NB / 4, 256, 0, stream>>>(team, gg, imp, gamma, beta, out_updated);
}

// Round 15
// 146.000 us; speedup vs baseline: 1.0780x; 1.0780x over previous
//
#include <hip/hip_runtime.h>
#include <hip/hip_bf16.h>

// B=16384, D=512, F=28, GIN=1053 (padded 1088 = 17*64)
// out[0 .. B*512)      = updated (LayerNorm result), fp32
// out[B*512 .. 2*B*512)= game_context = relu(x@Wproj^T+b), fp32
//
// Final configuration (round 11, best measured 144.8 µs):
//  - prep_all: X bf16 [NB][1088] + weight casts, one launch
//  - gemm_proj: 128x128 ring-2 BK=64, 2 blocks/CU, asm ds_read + per-step
//    vmcnt(0)+barrier (r9 schedule)
//  - gates_imp: gates (2048 blocks, r9 schedule, concat-K GRU algebra
//    gg=[s_r|s_z|i_n|h_n]) + importance GEMM as 256 tail blocks
//  - fuse_final2: GRU + blend + LayerNorm, 1 wave/row, vectorized

#define NB 16384
#define GINP 1088

typedef __bf16 bf16x8 __attribute__((ext_vector_type(8)));
typedef float f32x4 __attribute__((ext_vector_type(4)));
typedef unsigned short ushort8 __attribute__((ext_vector_type(8)));

__device__ __forceinline__ void gload_lds16(const void* g, void* l) {
  __builtin_amdgcn_global_load_lds(
      (const __attribute__((address_space(1))) void*)g,
      (__attribute__((address_space(3))) void*)l, 16, 0, 0);
}
// Inline-asm LDS read: opaque to hipcc's vmcnt/lgkmcnt dependency model.
// Caller must s_waitcnt lgkmcnt(0) + sched_barrier(0) before consuming.
__device__ __forceinline__ bf16x8 ds_read128(const unsigned short* l) {
  f32x4 r;
  asm volatile("ds_read_b128 %0, %1"
               : "=v"(r)
               : "v"((const __attribute__((address_space(3))) void*)l));
  bf16x8 out;
  __builtin_memcpy(&out, &r, 16);
  return out;
}
__device__ __forceinline__ float sigmoidf_(float x) { return 1.0f / (1.0f + expf(-x)); }
__device__ __forceinline__ float bf2f(unsigned short u) {
  unsigned int x = ((unsigned int)u) << 16;
  float f; __builtin_memcpy(&f, &x, 4); return f;
}

// ---------------- merged prep: X bf16 [NB][1088] + weight casts ----------------
#define PREP_X_BLOCKS ((NB * 136 + 255) / 256)
__global__ __launch_bounds__(256) void prep_all(
    const float* __restrict__ team, const float* __restrict__ opp,
    const float* __restrict__ gf, const float* __restrict__ won,
    const float* __restrict__ Wproj, const float* __restrict__ Wih,
    const float* __restrict__ Whh, const float* __restrict__ Wimp1,
    const float* __restrict__ bih, const float* __restrict__ bhh,
    __hip_bfloat16* __restrict__ X,
    __hip_bfloat16* __restrict__ Wpb, __hip_bfloat16* __restrict__ Wrz,
    __hip_bfloat16* __restrict__ Wn, __hip_bfloat16* __restrict__ Wimp1b,
    float* __restrict__ bcat) {
  if (blockIdx.x < PREP_X_BLOCKS) {
    long idx = (long)blockIdx.x * 256 + threadIdx.x;  // NB*136 slots of 8 cols
    if (idx >= (long)NB * 136) return;
    const int r = (int)(idx / 136);
    const int c8 = (int)(idx % 136) * 8;
    float v[8];
    if (c8 < 512) {
      float4 a = *(const float4*)&team[(size_t)r * 512 + c8];
      float4 b = *(const float4*)&team[(size_t)r * 512 + c8 + 4];
      v[0]=a.x; v[1]=a.y; v[2]=a.z; v[3]=a.w; v[4]=b.x; v[5]=b.y; v[6]=b.z; v[7]=b.w;
    } else if (c8 < 1024) {
      float4 a = *(const float4*)&opp[(size_t)r * 512 + (c8 - 512)];
      float4 b = *(const float4*)&opp[(size_t)r * 512 + (c8 - 512) + 4];
      v[0]=a.x; v[1]=a.y; v[2]=a.z; v[3]=a.w; v[4]=b.x; v[5]=b.y; v[6]=b.z; v[7]=b.w;
    } else if (c8 < 1048) {
      const int g0 = c8 - 1024;
#pragma unroll
      for (int e = 0; e < 8; ++e) v[e] = gf[(size_t)r * 28 + g0 + e];
    } else if (c8 == 1048) {
      v[0] = gf[(size_t)r * 28 + 24]; v[1] = gf[(size_t)r * 28 + 25];
      v[2] = gf[(size_t)r * 28 + 26]; v[3] = gf[(size_t)r * 28 + 27];
      v[4] = won[r]; v[5] = 0.f; v[6] = 0.f; v[7] = 0.f;
    } else {
#pragma unroll
      for (int e = 0; e < 8; ++e) v[e] = 0.f;
    }
    __hip_bfloat16 h[8];
#pragma unroll
    for (int e = 0; e < 8; ++e) h[e] = __float2bfloat16(v[e]);
    *(uint4*)&X[(size_t)r * GINP + c8] = *(const uint4*)h;
    return;
  }
  long idx = (long)(blockIdx.x - PREP_X_BLOCKS) * 256 + threadIdx.x;
  if (idx < 512L * 1088) {
    int r = (int)(idx / 1088), c = (int)(idx % 1088);
    Wpb[idx] = __float2bfloat16(c < 1053 ? Wproj[(size_t)r * 1053 + c] : 0.f);
    return;
  }
  idx -= 512L * 1088;
  if (idx < 1024L * 1024) {
    int q = (int)(idx >> 10), c = (int)(idx & 1023);
    float v = (c < 512) ? Wih[(size_t)q * 512 + c] : Whh[(size_t)q * 512 + (c - 512)];
    Wrz[idx] = __float2bfloat16(v);
    return;
  }
  idx -= 1024L * 1024;
  if (idx < 1024L * 512) {
    int q = (int)(idx / 512), c = (int)(idx % 512);
    float v = (q < 512) ? Wih[(size_t)(1024 + q) * 512 + c]
                        : Whh[(size_t)(1024 + q - 512) * 512 + c];
    Wn[idx] = __float2bfloat16(v);
    return;
  }
  idx -= 1024L * 512;
  if (idx < 128L * 512) { Wimp1b[idx] = __float2bfloat16(Wimp1[idx]); return; }
  idx -= 128L * 512;
  if (idx < 2048) {
    int j = (int)idx;
    float v;
    if (j < 1024) v = bih[j] + bhh[j];
    else if (j < 1536) v = bih[j];
    else v = bhh[j - 512];
    bcat[j] = v;
  }
}

// ---------------- projection GEMM: 128x128 tile, ring-2, 2 blocks/CU ----------
__global__ __launch_bounds__(256, 2) void gemm_proj(
    const __hip_bfloat16* __restrict__ A0,
    const __hip_bfloat16* __restrict__ W0, const float* __restrict__ bias,
    float* __restrict__ Cf, __hip_bfloat16* __restrict__ Cb) {
  __shared__ __align__(16) unsigned short ldsA[2 * 128 * 64];
  __shared__ __align__(16) unsigned short ldsB[2 * 128 * 64];

  const int tid = threadIdx.x;
  const int wid = tid >> 6, lane = tid & 63;
  const int wr = wid >> 1, wc = wid & 1;
  const int fl = lane & 15, kh = lane >> 4;
  const int prow_b = tid >> 3;
  const int gp = tid & 7;

  int bid = blockIdx.x;
  { const int cpx = gridDim.x >> 3; bid = (bid & 7) * cpx + (bid >> 3); }
  const int tm = bid >> 2, tn = bid & 3;
  const int m0 = tm * 128;
  const int NT = 17;

  const __hip_bfloat16* Wp = W0 + (size_t)tn * 128 * GINP;
  const float* bp = bias + tn * 128;

  auto stage = [&](int s) {
    const int k0 = s * 64;
    unsigned short* la = &ldsA[(s & 1) * 8192];
    unsigned short* lb = &ldsB[(s & 1) * 8192];
#pragma unroll
    for (int i = 0; i < 4; ++i) {
      const int row = i * 32 + prow_b;
      const int gl = gp ^ (row & 7);
      gload_lds16(A0 + (size_t)(m0 + row) * GINP + k0 + gl * 8,
                  la + (i * 32 + wid * 8) * 64);
      gload_lds16(Wp + (size_t)row * GINP + k0 + gl * 8,
                  lb + (i * 32 + wid * 8) * 64);
    }
  };

  f32x4 acc[4][4];
#pragma unroll
  for (int m = 0; m < 4; ++m)
#pragma unroll
    for (int n = 0; n < 4; ++n) acc[m][n] = (f32x4){0.f, 0.f, 0.f, 0.f};

  stage(0);

  for (int t = 0; t < NT; ++t) {
    const int sl = (t & 1) * 8192;
    asm volatile("s_waitcnt vmcnt(0)" ::: "memory");
    __builtin_amdgcn_s_barrier();
    if (t + 1 < NT) stage(t + 1);

    bf16x8 af[2][4], bfr[2][4];
#pragma unroll
    for (int kk = 0; kk < 2; ++kk) {
#pragma unroll
      for (int m = 0; m < 4; ++m) {
        const int r = wr * 64 + m * 16 + fl;
        const int g = (kk * 4 + kh) ^ (r & 7);
        af[kk][m] = ds_read128(&ldsA[sl + r * 64 + g * 8]);
      }
#pragma unroll
      for (int n = 0; n < 4; ++n) {
        const int r = wc * 64 + n * 16 + fl;
        const int g = (kk * 4 + kh) ^ (r & 7);
        bfr[kk][n] = ds_read128(&ldsB[sl + r * 64 + g * 8]);
      }
    }
    asm volatile("s_waitcnt lgkmcnt(0)" ::: "memory");
    __builtin_amdgcn_sched_barrier(0);
    __builtin_amdgcn_s_setprio(1);
#pragma unroll
    for (int kk = 0; kk < 2; ++kk)
#pragma unroll
      for (int m = 0; m < 4; ++m)
#pragma unroll
        for (int n = 0; n < 4; ++n)
          acc[m][n] = __builtin_amdgcn_mfma_f32_16x16x32_bf16(af[kk][m], bfr[kk][n], acc[m][n], 0, 0, 0);
    __builtin_amdgcn_s_setprio(0);
  }

  // Epilogue (verified): C/D map col = lane&15, row = (lane>>4)*4 + j
#pragma unroll
  for (int m = 0; m < 4; ++m)
#pragma unroll
    for (int n = 0; n < 4; ++n)
#pragma unroll
      for (int j = 0; j < 4; ++j) {
        const int lrow = wr * 64 + m * 16 + kh * 4 + j;
        const int lcol = wc * 64 + n * 16 + fl;
        const size_t grow = (size_t)(m0 + lrow);
        float v = acc[m][n][j] + bp[lcol];
        v = fmaxf(v, 0.f);
        Cf[grow * 512 + tn * 128 + lcol] = v;
        Cb[grow * 512 + tn * 128 + lcol] = __float2bfloat16(v);
      }
}

// ---------------- gates GEMM + fused importance blocks ----------------
// blocks 0..2047: gates 128x128 ring-2 (r9 schedule/indices);
// blocks 2048..2303: importance (imp = sigmoid(relu(P@W1^T+b1)@w2+b2), 64 rows/block).
__global__ __launch_bounds__(256, 2) void gates_imp(
    const __hip_bfloat16* __restrict__ Pm, const __hip_bfloat16* __restrict__ Xb,
    const __hip_bfloat16* __restrict__ Wrz, const __hip_bfloat16* __restrict__ Wn,
    const float* __restrict__ bcat, __hip_bfloat16* __restrict__ gg,
    const __hip_bfloat16* __restrict__ Wimp1b, const float* __restrict__ b1,
    const float* __restrict__ w2, const float* __restrict__ b2,
    float* __restrict__ imp) {
  __shared__ __align__(16) unsigned short lds[32768];  // 64KB

  const int tid = threadIdx.x;
  const int wid = tid >> 6, lane = tid & 63;
  const int wr = wid >> 1, wc = wid & 1;
  const int fl = lane & 15, kh = lane >> 4;

  if (blockIdx.x >= 2048) {
    // ---------- importance path ----------
    unsigned short* ldsA = lds;            // 64x64
    unsigned short* ldsB = lds + 4096;     // 128x64
    float* sdot = (float*)(lds + 4096 + 8192);
    const int srow = lane >> 3, scol = (lane & 7) * 8;
    const int m0 = (blockIdx.x - 2048) * 64;

    if (tid < 64) sdot[tid] = 0.f;

    f32x4 acc[2][4];
#pragma unroll
    for (int m = 0; m < 2; ++m)
#pragma unroll
      for (int n = 0; n < 4; ++n) acc[m][n] = (f32x4){0.f, 0.f, 0.f, 0.f};

    for (int kt = 0; kt < 8; ++kt) {
      const int k0 = kt * 64;
#pragma unroll
      for (int c = 0; c < 2; ++c) {
        const int rgrp = c * 4 + wid;
        const int row = rgrp * 8 + srow;
        gload_lds16(Pm + (size_t)(m0 + row) * 512 + k0 + scol, (char*)ldsA + rgrp * 1024);
      }
#pragma unroll
      for (int c = 0; c < 4; ++c) {
        const int rgrp = c * 4 + wid;
        const int row = rgrp * 8 + srow;
        gload_lds16(Wimp1b + (size_t)row * 512 + k0 + scol, (char*)ldsB + rgrp * 1024);
      }
      __syncthreads();
#pragma unroll
      for (int kk = 0; kk < 2; ++kk) {
        bf16x8 af[2], bfr[4];
#pragma unroll
        for (int m = 0; m < 2; ++m)
          af[m] = *(const bf16x8*)&ldsA[(wr * 32 + m * 16 + fl) * 64 + kk * 32 + kh * 8];
#pragma unroll
        for (int n = 0; n < 4; ++n)
          bfr[n] = *(const bf16x8*)&ldsB[(wc * 64 + n * 16 + fl) * 64 + kk * 32 + kh * 8];
#pragma unroll
        for (int m = 0; m < 2; ++m)
#pragma unroll
          for (int n = 0; n < 4; ++n)
            acc[m][n] = __builtin_amdgcn_mfma_f32_16x16x32_bf16(af[m], bfr[n], acc[m][n], 0, 0, 0);
      }
      __syncthreads();
    }
#pragma unroll
    for (int m = 0; m < 2; ++m)
#pragma unroll
      for (int j = 0; j < 4; ++j) {
        float p = 0.f;
#pragma unroll
        for (int n = 0; n < 4; ++n) {
          const int lcol = wc * 64 + n * 16 + fl;
          const float v = fmaxf(acc[m][n][j] + b1[lcol], 0.f);
          p += v * w2[lcol];
        }
        atomicAdd(&sdot[wr * 32 + m * 16 + kh * 4 + j], p);
      }
    __syncthreads();
    if (tid < 64) imp[m0 + tid] = sigmoidf_(sdot[tid] + b2[0]);
    return;
  }

  // ---------- gates path (round-9 verified) ----------
  unsigned short* ldsA = lds;            // 2 slots x 128x64
  unsigned short* ldsB = lds + 16384;    // 2 slots x 128x64
  const int prow_b = tid >> 3;
  const int gp = tid & 7;

  int bid = blockIdx.x;
  bid = (bid & 7) * 256 + (bid >> 3);    // XCD swizzle over 2048 blocks
  const int tm = bid >> 4, tn = bid & 15;
  const int m0 = tm * 128;

  const __hip_bfloat16* Wp; int ldw, NT;
  if (tn < 8) { Wp = Wrz + (size_t)tn * 128 * 1024; ldw = 1024; NT = 16; }
  else        { Wp = Wn + (size_t)(tn - 8) * 128 * 512; ldw = 512; NT = 8; }
  const float* bp = bcat + tn * 128;

  auto stage = [&](int s) {
    const int kW = s * 64;
    const __hip_bfloat16* Ap; int lda; int kA;
    if (tn < 8) {
      if (s < 8) { Ap = Pm; lda = 512; kA = s * 64; }
      else       { Ap = Xb; lda = GINP; kA = (s - 8) * 64; }
    } else if (tn < 12) { Ap = Pm; lda = 512; kA = s * 64; }
    else                { Ap = Xb; lda = GINP; kA = s * 64; }
    unsigned short* la = &ldsA[(s & 1) * 8192];
    unsigned short* lb = &ldsB[(s & 1) * 8192];
#pragma unroll
    for (int i = 0; i < 4; ++i) {
      const int row = i * 32 + prow_b;
      const int gl = gp ^ (row & 7);
      gload_lds16(Ap + (size_t)(m0 + row) * lda + kA + gl * 8,
                  la + (i * 32 + wid * 8) * 64);
      gload_lds16(Wp + (size_t)row * ldw + kW + gl * 8,
                  lb + (i * 32 + wid * 8) * 64);
    }
  };

  f32x4 acc[4][4];
#pragma unroll
  for (int m = 0; m < 4; ++m)
#pragma unroll
    for (int n = 0; n < 4; ++n) acc[m][n] = (f32x4){0.f, 0.f, 0.f, 0.f};

  stage(0);

  for (int t = 0; t < NT; ++t) {
    const int sl = (t & 1) * 8192;
    asm volatile("s_waitcnt vmcnt(0)" ::: "memory");
    __builtin_amdgcn_s_barrier();
    if (t + 1 < NT) stage(t + 1);

    bf16x8 af[2][4], bfr[2][4];
#pragma unroll
    for (int kk = 0; kk < 2; ++kk) {
#pragma unroll
      for (int m = 0; m < 4; ++m) {
        const int r = wr * 64 + m * 16 + fl;
        const int g = (kk * 4 + kh) ^ (r & 7);
        af[kk][m] = ds_read128(&ldsA[sl + r * 64 + g * 8]);
      }
#pragma unroll
      for (int n = 0; n < 4; ++n) {
        const int r = wc * 64 + n * 16 + fl;
        const int g = (kk * 4 + kh) ^ (r & 7);
        bfr[kk][n] = ds_read128(&ldsB[sl + r * 64 + g * 8]);
      }
    }
    asm volatile("s_waitcnt lgkmcnt(0)" ::: "memory");
    __builtin_amdgcn_sched_barrier(0);
    __builtin_amdgcn_s_setprio(1);
#pragma unroll
    for (int kk = 0; kk < 2; ++kk)
#pragma unroll
      for (int m = 0; m < 4; ++m)
#pragma unroll
        for (int n = 0; n < 4; ++n)
          acc[m][n] = __builtin_amdgcn_mfma_f32_16x16x32_bf16(af[kk][m], bfr[kk][n], acc[m][n], 0, 0, 0);
    __builtin_amdgcn_s_setprio(0);
  }

  // Epilogue (round-9 verified)
#pragma unroll
  for (int m = 0; m < 4; ++m)
#pragma unroll
    for (int n = 0; n < 4; ++n)
#pragma unroll
      for (int j = 0; j < 4; ++j) {
        const int lrow = wr * 64 + m * 16 + kh * 4 + j;
        const int lcol = wc * 64 + n * 16 + fl;
        gg[(size_t)(m0 + lrow) * 2048 + tn * 128 + lcol] =
            __float2bfloat16(acc[m][n][j] + bp[lcol]);
      }
}

// ---------------- fused GRU + blend + LayerNorm (vectorized, 1 wave/row) ----------------
// gg [NB][2048]: [s_r | s_z | i_n | h_n]
__global__ __launch_bounds__(256) void fuse_final2(
    const float* __restrict__ team, const __hip_bfloat16* __restrict__ gg,
    const float* __restrict__ imp, const float* __restrict__ gamma,
    const float* __restrict__ beta, float* __restrict__ out) {
  const int row = blockIdx.x * 4 + (threadIdx.x >> 6);
  const int lane = threadIdx.x & 63;
  const size_t gb = (size_t)row * 2048 + lane * 8;
  ushort8 sr = *(const ushort8*)&gg[gb];
  ushort8 szv = *(const ushort8*)&gg[gb + 512];
  ushort8 inn = *(const ushort8*)&gg[gb + 1024];
  ushort8 hnn = *(const ushort8*)&gg[gb + 1536];
  float4 t0 = *(const float4*)&team[(size_t)row * 512 + lane * 8];
  float4 t1 = *(const float4*)&team[(size_t)row * 512 + lane * 8 + 4];
  const float im = imp[row];
  float tv[8] = {t0.x, t0.y, t0.z, t0.w, t1.x, t1.y, t1.z, t1.w};
  float u[8];
  float s = 0.f, ss = 0.f;
#pragma unroll
  for (int e = 0; e < 8; ++e) {
    const float rg = sigmoidf_(bf2f(sr[e]));
    const float zg = sigmoidf_(bf2f(szv[e]));
    const float ng = tanhf(bf2f(inn[e]) + rg * bf2f(hnn[e]));
    const float ne = (1.f - zg) * ng + zg * tv[e];
    const float uu = tv[e] + im * (ne - tv[e]);
    u[e] = uu; s += uu; ss += uu * uu;
  }
#pragma unroll
  for (int off = 32; off; off >>= 1) {
    s += __shfl_down(s, off);
    ss += __shfl_down(ss, off);
  }
  s = __shfl(s, 0); ss = __shfl(ss, 0);
  const float mu = s * (1.f / 512.f);
  const float inv = rsqrtf(ss * (1.f / 512.f) - mu * mu + 1e-5f);
  float4 g0 = *(const float4*)&gamma[lane * 8], g1 = *(const float4*)&gamma[lane * 8 + 4];
  float4 b0 = *(const float4*)&beta[lane * 8], b1 = *(const float4*)&beta[lane * 8 + 4];
  float gv[8] = {g0.x, g0.y, g0.z, g0.w, g1.x, g1.y, g1.z, g1.w};
  float bv[8] = {b0.x, b0.y, b0.z, b0.w, b1.x, b1.y, b1.z, b1.w};
  float4 o0, o1;
  o0.x = gv[0] * (u[0] - mu) * inv + bv[0];
  o0.y = gv[1] * (u[1] - mu) * inv + bv[1];
  o0.z = gv[2] * (u[2] - mu) * inv + bv[2];
  o0.w = gv[3] * (u[3] - mu) * inv + bv[3];
  o1.x = gv[4] * (u[4] - mu) * inv + bv[4];
  o1.y = gv[5] * (u[5] - mu) * inv + bv[5];
  o1.z = gv[6] * (u[6] - mu) * inv + bv[6];
  o1.w = gv[7] * (u[7] - mu) * inv + bv[7];
  *(float4*)&out[(size_t)row * 512 + lane * 8] = o0;
  *(float4*)&out[(size_t)row * 512 + lane * 8 + 4] = o1;
}

// ---------------- launch ----------------
extern "C" void kernel_launch(void* const* d_in, const int* in_sizes, int n_in,
                              void* d_out, int out_size, void* d_ws, size_t ws_size,
                              hipStream_t stream) {
  const float* team   = (const float*)d_in[0];
  const float* opp    = (const float*)d_in[1];
  const float* gf     = (const float*)d_in[2];
  const float* won    = (const float*)d_in[3];
  const float* W_proj = (const float*)d_in[4];
  const float* b_proj = (const float*)d_in[5];
  const float* W_ih   = (const float*)d_in[6];
  const float* b_ih   = (const float*)d_in[7];
  const float* W_hh   = (const float*)d_in[8];
  const float* b_hh   = (const float*)d_in[9];
  const float* gamma  = (const float*)d_in[10];
  const float* beta   = (const float*)d_in[11];
  const float* W_imp1 = (const float*)d_in[12];
  const float* b_imp1 = (const float*)d_in[13];
  const float* W_imp2 = (const float*)d_in[14];
  const float* b_imp2 = (const float*)d_in[15];

  char* ws = (char*)d_ws;
  size_t o = 0;
  __hip_bfloat16* Xbf    = (__hip_bfloat16*)(ws + o); o += (size_t)NB * GINP * 2;
  __hip_bfloat16* Wpb    = (__hip_bfloat16*)(ws + o); o += (size_t)512 * GINP * 2;
  __hip_bfloat16* Wrz    = (__hip_bfloat16*)(ws + o); o += (size_t)1024 * 1024 * 2;
  __hip_bfloat16* Wn     = (__hip_bfloat16*)(ws + o); o += (size_t)1024 * 512 * 2;
  __hip_bfloat16* Wimp1b = (__hip_bfloat16*)(ws + o); o += (size_t)128 * 512 * 2;
  float*          bcat   = (float*)(ws + o);          o += (size_t)2048 * 4;
  __hip_bfloat16* Pbf    = (__hip_bfloat16*)(ws + o); o += (size_t)NB * 512 * 2;
  float*          imp    = (float*)(ws + o);          o += (size_t)NB * 4;
  __hip_bfloat16* gg     = (__hip_bfloat16*)(ws + o); o += (size_t)NB * 2048 * 2;

  float* out_updated = (float*)d_out;
  float* out_ctx     = (float*)d_out + (size_t)NB * 512;

  {
    const long wtotal = 512L * 1088 + 1024L * 1024 + 1024L * 512 + 128L * 512 + 2048;
    const int wblocks = (int)((wtotal + 255) / 256);
    prep_all<<<PREP_X_BLOCKS + wblocks, 256, 0, stream>>>(
        team, opp, gf, won, W_proj, W_ih, W_hh, W_imp1, b_ih, b_hh,
        Xbf, Wpb, Wrz, Wn, Wimp1b, bcat);
  }
  // projected = relu(X @ Wpb^T + b_proj): M=16384, N=512, K=1088 -> 128x4 = 512 blocks
  gemm_proj<<<512, 256, 0, stream>>>(Xbf, Wpb, b_proj, out_ctx, Pbf);
  // gates (2048 blocks) + importance (256 tail blocks) in one launch
  gates_imp<<<2304, 256, 0, stream>>>(Pbf, Xbf, Wrz, Wn, bcat, gg,
                                      Wimp1b, b_imp1, W_imp2, b_imp2, imp);
  fuse_final2<<<NB / 4, 256, 0, stream>>>(team, gg, imp, gamma, beta, out_updated);
}

// Round 16
// 143.372 us; speedup vs baseline: 1.0978x; 1.0183x over previous
//
#include <hip/hip_runtime.h>
#include <hip/hip_bf16.h>

// B=16384, D=512, F=28, GIN=1053 (padded 1088 = 17*64)
// out[0 .. B*512)      = updated (LayerNorm result), fp32
// out[B*512 .. 2*B*512)= game_context = relu(x@Wproj^T+b), fp32
//
// r16 = r11 geometry (128x128, BK=64, ring-2, 2 blocks/CU) with the r8-proven
// two-barrier counted-vmcnt step: b1 -> stage(t+1) -> vmcnt(8) -> b2 -> reads.
// Loads stay in flight across the MFMA phase (never drained to 0 mid-loop).

#define NB 16384
#define GINP 1088

typedef __bf16 bf16x8 __attribute__((ext_vector_type(8)));
typedef float f32x4 __attribute__((ext_vector_type(4)));
typedef unsigned short ushort8 __attribute__((ext_vector_type(8)));

__device__ __forceinline__ void gload_lds16(const void* g, void* l) {
  __builtin_amdgcn_global_load_lds(
      (const __attribute__((address_space(1))) void*)g,
      (__attribute__((address_space(3))) void*)l, 16, 0, 0);
}
// Inline-asm LDS read: opaque to hipcc's vmcnt/lgkmcnt dependency model.
// Caller must s_waitcnt lgkmcnt(0) + sched_barrier(0) before consuming.
__device__ __forceinline__ bf16x8 ds_read128(const unsigned short* l) {
  f32x4 r;
  asm volatile("ds_read_b128 %0, %1"
               : "=v"(r)
               : "v"((const __attribute__((address_space(3))) void*)l));
  bf16x8 out;
  __builtin_memcpy(&out, &r, 16);
  return out;
}
__device__ __forceinline__ float sigmoidf_(float x) { return 1.0f / (1.0f + expf(-x)); }
__device__ __forceinline__ float bf2f(unsigned short u) {
  unsigned int x = ((unsigned int)u) << 16;
  float f; __builtin_memcpy(&f, &x, 4); return f;
}

// ---------------- merged prep: X bf16 [NB][1088] + weight casts ----------------
#define PREP_X_BLOCKS ((NB * 136 + 255) / 256)
__global__ __launch_bounds__(256) void prep_all(
    const float* __restrict__ team, const float* __restrict__ opp,
    const float* __restrict__ gf, const float* __restrict__ won,
    const float* __restrict__ Wproj, const float* __restrict__ Wih,
    const float* __restrict__ Whh, const float* __restrict__ Wimp1,
    const float* __restrict__ bih, const float* __restrict__ bhh,
    __hip_bfloat16* __restrict__ X,
    __hip_bfloat16* __restrict__ Wpb, __hip_bfloat16* __restrict__ Wrz,
    __hip_bfloat16* __restrict__ Wn, __hip_bfloat16* __restrict__ Wimp1b,
    float* __restrict__ bcat) {
  if (blockIdx.x < PREP_X_BLOCKS) {
    long idx = (long)blockIdx.x * 256 + threadIdx.x;  // NB*136 slots of 8 cols
    if (idx >= (long)NB * 136) return;
    const int r = (int)(idx / 136);
    const int c8 = (int)(idx % 136) * 8;
    float v[8];
    if (c8 < 512) {
      float4 a = *(const float4*)&team[(size_t)r * 512 + c8];
      float4 b = *(const float4*)&team[(size_t)r * 512 + c8 + 4];
      v[0]=a.x; v[1]=a.y; v[2]=a.z; v[3]=a.w; v[4]=b.x; v[5]=b.y; v[6]=b.z; v[7]=b.w;
    } else if (c8 < 1024) {
      float4 a = *(const float4*)&opp[(size_t)r * 512 + (c8 - 512)];
      float4 b = *(const float4*)&opp[(size_t)r * 512 + (c8 - 512) + 4];
      v[0]=a.x; v[1]=a.y; v[2]=a.z; v[3]=a.w; v[4]=b.x; v[5]=b.y; v[6]=b.z; v[7]=b.w;
    } else if (c8 < 1048) {
      const int g0 = c8 - 1024;
#pragma unroll
      for (int e = 0; e < 8; ++e) v[e] = gf[(size_t)r * 28 + g0 + e];
    } else if (c8 == 1048) {
      v[0] = gf[(size_t)r * 28 + 24]; v[1] = gf[(size_t)r * 28 + 25];
      v[2] = gf[(size_t)r * 28 + 26]; v[3] = gf[(size_t)r * 28 + 27];
      v[4] = won[r]; v[5] = 0.f; v[6] = 0.f; v[7] = 0.f;
    } else {
#pragma unroll
      for (int e = 0; e < 8; ++e) v[e] = 0.f;
    }
    __hip_bfloat16 h[8];
#pragma unroll
    for (int e = 0; e < 8; ++e) h[e] = __float2bfloat16(v[e]);
    *(uint4*)&X[(size_t)r * GINP + c8] = *(const uint4*)h;
    return;
  }
  long idx = (long)(blockIdx.x - PREP_X_BLOCKS) * 256 + threadIdx.x;
  if (idx < 512L * 1088) {
    int r = (int)(idx / 1088), c = (int)(idx % 1088);
    Wpb[idx] = __float2bfloat16(c < 1053 ? Wproj[(size_t)r * 1053 + c] : 0.f);
    return;
  }
  idx -= 512L * 1088;
  if (idx < 1024L * 1024) {
    int q = (int)(idx >> 10), c = (int)(idx & 1023);
    float v = (c < 512) ? Wih[(size_t)q * 512 + c] : Whh[(size_t)q * 512 + (c - 512)];
    Wrz[idx] = __float2bfloat16(v);
    return;
  }
  idx -= 1024L * 1024;
  if (idx < 1024L * 512) {
    int q = (int)(idx / 512), c = (int)(idx % 512);
    float v = (q < 512) ? Wih[(size_t)(1024 + q) * 512 + c]
                        : Whh[(size_t)(1024 + q - 512) * 512 + c];
    Wn[idx] = __float2bfloat16(v);
    return;
  }
  idx -= 1024L * 512;
  if (idx < 128L * 512) { Wimp1b[idx] = __float2bfloat16(Wimp1[idx]); return; }
  idx -= 128L * 512;
  if (idx < 2048) {
    int j = (int)idx;
    float v;
    if (j < 1024) v = bih[j] + bhh[j];
    else if (j < 1536) v = bih[j];
    else v = bhh[j - 512];
    bcat[j] = v;
  }
}

// ---------------- projection GEMM: 128x128 tile, ring-2, two-barrier counted vmcnt ------
__global__ __launch_bounds__(256, 2) void gemm_proj(
    const __hip_bfloat16* __restrict__ A0,
    const __hip_bfloat16* __restrict__ W0, const float* __restrict__ bias,
    float* __restrict__ Cf, __hip_bfloat16* __restrict__ Cb) {
  __shared__ __align__(16) unsigned short ldsA[2 * 128 * 64];
  __shared__ __align__(16) unsigned short ldsB[2 * 128 * 64];

  const int tid = threadIdx.x;
  const int wid = tid >> 6, lane = tid & 63;
  const int wr = wid >> 1, wc = wid & 1;
  const int fl = lane & 15, kh = lane >> 4;
  const int prow_b = tid >> 3;
  const int gp = tid & 7;

  int bid = blockIdx.x;
  { const int cpx = gridDim.x >> 3; bid = (bid & 7) * cpx + (bid >> 3); }
  const int tm = bid >> 2, tn = bid & 3;
  const int m0 = tm * 128;
  const int NT = 17;

  const __hip_bfloat16* Wp = W0 + (size_t)tn * 128 * GINP;
  const float* bp = bias + tn * 128;

  auto stage = [&](int s) {
    const int k0 = s * 64;
    unsigned short* la = &ldsA[(s & 1) * 8192];
    unsigned short* lb = &ldsB[(s & 1) * 8192];
#pragma unroll
    for (int i = 0; i < 4; ++i) {
      const int row = i * 32 + prow_b;
      const int gl = gp ^ (row & 7);
      gload_lds16(A0 + (size_t)(m0 + row) * GINP + k0 + gl * 8,
                  la + (i * 32 + wid * 8) * 64);
      gload_lds16(Wp + (size_t)row * GINP + k0 + gl * 8,
                  lb + (i * 32 + wid * 8) * 64);
    }
  };

  f32x4 acc[4][4];
#pragma unroll
  for (int m = 0; m < 4; ++m)
#pragma unroll
    for (int n = 0; n < 4; ++n) acc[m][n] = (f32x4){0.f, 0.f, 0.f, 0.f};

  stage(0);

  for (int t = 0; t < NT; ++t) {
    const int sl = (t & 1) * 8192;
    __builtin_amdgcn_s_barrier();   // b1: slot^1 reads (t-1) retired by all waves
    if (t + 1 < NT) {
      stage(t + 1);                 // 8 loads -> slot^1; stay in flight thru MFMA(t)
      asm volatile("s_waitcnt vmcnt(8)" ::: "memory");  // own stage(t) landed
    } else {
      asm volatile("s_waitcnt vmcnt(0)" ::: "memory");
    }
    __builtin_amdgcn_s_barrier();   // b2: ALL waves' stage(t) landed (vmcnt per-wave)

    bf16x8 af[2][4], bfr[2][4];
#pragma unroll
    for (int kk = 0; kk < 2; ++kk) {
#pragma unroll
      for (int m = 0; m < 4; ++m) {
        const int r = wr * 64 + m * 16 + fl;
        const int g = (kk * 4 + kh) ^ (r & 7);
        af[kk][m] = ds_read128(&ldsA[sl + r * 64 + g * 8]);
      }
#pragma unroll
      for (int n = 0; n < 4; ++n) {
        const int r = wc * 64 + n * 16 + fl;
        const int g = (kk * 4 + kh) ^ (r & 7);
        bfr[kk][n] = ds_read128(&ldsB[sl + r * 64 + g * 8]);
      }
    }
    asm volatile("s_waitcnt lgkmcnt(0)" ::: "memory");
    __builtin_amdgcn_sched_barrier(0);
    __builtin_amdgcn_s_setprio(1);
#pragma unroll
    for (int kk = 0; kk < 2; ++kk)
#pragma unroll
      for (int m = 0; m < 4; ++m)
#pragma unroll
        for (int n = 0; n < 4; ++n)
          acc[m][n] = __builtin_amdgcn_mfma_f32_16x16x32_bf16(af[kk][m], bfr[kk][n], acc[m][n], 0, 0, 0);
    __builtin_amdgcn_s_setprio(0);
  }

  // Epilogue (verified): C/D map col = lane&15, row = (lane>>4)*4 + j
#pragma unroll
  for (int m = 0; m < 4; ++m)
#pragma unroll
    for (int n = 0; n < 4; ++n)
#pragma unroll
      for (int j = 0; j < 4; ++j) {
        const int lrow = wr * 64 + m * 16 + kh * 4 + j;
        const int lcol = wc * 64 + n * 16 + fl;
        const size_t grow = (size_t)(m0 + lrow);
        float v = acc[m][n][j] + bp[lcol];
        v = fmaxf(v, 0.f);
        Cf[grow * 512 + tn * 128 + lcol] = v;
        Cb[grow * 512 + tn * 128 + lcol] = __float2bfloat16(v);
      }
}

// ---------------- gates GEMM + fused importance blocks ----------------
// blocks 0..2047: gates 128x128 ring-2, two-barrier counted vmcnt(8);
// blocks 2048..2303: importance (imp = sigmoid(relu(P@W1^T+b1)@w2+b2), 64 rows/block).
__global__ __launch_bounds__(256, 2) void gates_imp(
    const __hip_bfloat16* __restrict__ Pm, const __hip_bfloat16* __restrict__ Xb,
    const __hip_bfloat16* __restrict__ Wrz, const __hip_bfloat16* __restrict__ Wn,
    const float* __restrict__ bcat, __hip_bfloat16* __restrict__ gg,
    const __hip_bfloat16* __restrict__ Wimp1b, const float* __restrict__ b1,
    const float* __restrict__ w2, const float* __restrict__ b2,
    float* __restrict__ imp) {
  __shared__ __align__(16) unsigned short lds[32768];  // 64KB

  const int tid = threadIdx.x;
  const int wid = tid >> 6, lane = tid & 63;
  const int wr = wid >> 1, wc = wid & 1;
  const int fl = lane & 15, kh = lane >> 4;

  if (blockIdx.x >= 2048) {
    // ---------- importance path (r11 verified) ----------
    unsigned short* ldsA = lds;            // 64x64
    unsigned short* ldsB = lds + 4096;     // 128x64
    float* sdot = (float*)(lds + 4096 + 8192);
    const int srow = lane >> 3, scol = (lane & 7) * 8;
    const int m0 = (blockIdx.x - 2048) * 64;

    if (tid < 64) sdot[tid] = 0.f;

    f32x4 acc[2][4];
#pragma unroll
    for (int m = 0; m < 2; ++m)
#pragma unroll
      for (int n = 0; n < 4; ++n) acc[m][n] = (f32x4){0.f, 0.f, 0.f, 0.f};

    for (int kt = 0; kt < 8; ++kt) {
      const int k0 = kt * 64;
#pragma unroll
      for (int c = 0; c < 2; ++c) {
        const int rgrp = c * 4 + wid;
        const int row = rgrp * 8 + srow;
        gload_lds16(Pm + (size_t)(m0 + row) * 512 + k0 + scol, (char*)ldsA + rgrp * 1024);
      }
#pragma unroll
      for (int c = 0; c < 4; ++c) {
        const int rgrp = c * 4 + wid;
        const int row = rgrp * 8 + srow;
        gload_lds16(Wimp1b + (size_t)row * 512 + k0 + scol, (char*)ldsB + rgrp * 1024);
      }
      __syncthreads();
#pragma unroll
      for (int kk = 0; kk < 2; ++kk) {
        bf16x8 af[2], bfr[4];
#pragma unroll
        for (int m = 0; m < 2; ++m)
          af[m] = *(const bf16x8*)&ldsA[(wr * 32 + m * 16 + fl) * 64 + kk * 32 + kh * 8];
#pragma unroll
        for (int n = 0; n < 4; ++n)
          bfr[n] = *(const bf16x8*)&ldsB[(wc * 64 + n * 16 + fl) * 64 + kk * 32 + kh * 8];
#pragma unroll
        for (int m = 0; m < 2; ++m)
#pragma unroll
          for (int n = 0; n < 4; ++n)
            acc[m][n] = __builtin_amdgcn_mfma_f32_16x16x32_bf16(af[m], bfr[n], acc[m][n], 0, 0, 0);
      }
      __syncthreads();
    }
#pragma unroll
    for (int m = 0; m < 2; ++m)
#pragma unroll
      for (int j = 0; j < 4; ++j) {
        float p = 0.f;
#pragma unroll
        for (int n = 0; n < 4; ++n) {
          const int lcol = wc * 64 + n * 16 + fl;
          const float v = fmaxf(acc[m][n][j] + b1[lcol], 0.f);
          p += v * w2[lcol];
        }
        atomicAdd(&sdot[wr * 32 + m * 16 + kh * 4 + j], p);
      }
    __syncthreads();
    if (tid < 64) imp[m0 + tid] = sigmoidf_(sdot[tid] + b2[0]);
    return;
  }

  // ---------- gates path ----------
  unsigned short* ldsA = lds;            // 2 slots x 128x64
  unsigned short* ldsB = lds + 16384;    // 2 slots x 128x64
  const int prow_b = tid >> 3;
  const int gp = tid & 7;

  int bid = blockIdx.x;
  bid = (bid & 7) * 256 + (bid >> 3);    // XCD swizzle over 2048 blocks
  const int tm = bid >> 4, tn = bid & 15;
  const int m0 = tm * 128;

  const __hip_bfloat16* Wp; int ldw, NT;
  if (tn < 8) { Wp = Wrz + (size_t)tn * 128 * 1024; ldw = 1024; NT = 16; }
  else        { Wp = Wn + (size_t)(tn - 8) * 128 * 512; ldw = 512; NT = 8; }
  const float* bp = bcat + tn * 128;

  auto stage = [&](int s) {
    const int kW = s * 64;
    const __hip_bfloat16* Ap; int lda; int kA;
    if (tn < 8) {
      if (s < 8) { Ap = Pm; lda = 512; kA = s * 64; }
      else       { Ap = Xb; lda = GINP; kA = (s - 8) * 64; }
    } else if (tn < 12) { Ap = Pm; lda = 512; kA = s * 64; }
    else                { Ap = Xb; lda = GINP; kA = s * 64; }
    unsigned short* la = &ldsA[(s & 1) * 8192];
    unsigned short* lb = &ldsB[(s & 1) * 8192];
#pragma unroll
    for (int i = 0; i < 4; ++i) {
      const int row = i * 32 + prow_b;
      const int gl = gp ^ (row & 7);
      gload_lds16(Ap + (size_t)(m0 + row) * lda + kA + gl * 8,
                  la + (i * 32 + wid * 8) * 64);
      gload_lds16(Wp + (size_t)row * ldw + kW + gl * 8,
                  lb + (i * 32 + wid * 8) * 64);
    }
  };

  f32x4 acc[4][4];
#pragma unroll
  for (int m = 0; m < 4; ++m)
#pragma unroll
    for (int n = 0; n < 4; ++n) acc[m][n] = (f32x4){0.f, 0.f, 0.f, 0.f};

  stage(0);

  for (int t = 0; t < NT; ++t) {
    const int sl = (t & 1) * 8192;
    __builtin_amdgcn_s_barrier();   // b1: slot^1 reads (t-1) retired by all waves
    if (t + 1 < NT) {
      stage(t + 1);                 // 8 loads -> slot^1; in flight through MFMA(t)
      asm volatile("s_waitcnt vmcnt(8)" ::: "memory");  // own stage(t) landed
    } else {
      asm volatile("s_waitcnt vmcnt(0)" ::: "memory");
    }
    __builtin_amdgcn_s_barrier();   // b2: ALL waves' stage(t) landed

    bf16x8 af[2][4], bfr[2][4];
#pragma unroll
    for (int kk = 0; kk < 2; ++kk) {
#pragma unroll
      for (int m = 0; m < 4; ++m) {
        const int r = wr * 64 + m * 16 + fl;
        const int g = (kk * 4 + kh) ^ (r & 7);
        af[kk][m] = ds_read128(&ldsA[sl + r * 64 + g * 8]);
      }
#pragma unroll
      for (int n = 0; n < 4; ++n) {
        const int r = wc * 64 + n * 16 + fl;
        const int g = (kk * 4 + kh) ^ (r & 7);
        bfr[kk][n] = ds_read128(&ldsB[sl + r * 64 + g * 8]);
      }
    }
    asm volatile("s_waitcnt lgkmcnt(0)" ::: "memory");
    __builtin_amdgcn_sched_barrier(0);
    __builtin_amdgcn_s_setprio(1);
#pragma unroll
    for (int kk = 0; kk < 2; ++kk)
#pragma unroll
      for (int m = 0; m < 4; ++m)
#pragma unroll
        for (int n = 0; n < 4; ++n)
          acc[m][n] = __builtin_amdgcn_mfma_f32_16x16x32_bf16(af[kk][m], bfr[kk][n], acc[m][n], 0, 0, 0);
    __builtin_amdgcn_s_setprio(0);
  }

  // Epilogue (verified)
#pragma unroll
  for (int m = 0; m < 4; ++m)
#pragma unroll
    for (int n = 0; n < 4; ++n)
#pragma unroll
      for (int j = 0; j < 4; ++j) {
        const int lrow = wr * 64 + m * 16 + kh * 4 + j;
        const int lcol = wc * 64 + n * 16 + fl;
        gg[(size_t)(m0 + lrow) * 2048 + tn * 128 + lcol] =
            __float2bfloat16(acc[m][n][j] + bp[lcol]);
      }
}

// ---------------- fused GRU + blend + LayerNorm (vectorized, 1 wave/row) ----------------
// gg [NB][2048]: [s_r | s_z | i_n | h_n]
__global__ __launch_bounds__(256) void fuse_final2(
    const float* __restrict__ team, const __hip_bfloat16* __restrict__ gg,
    const float* __restrict__ imp, const float* __restrict__ gamma,
    const float* __restrict__ beta, float* __restrict__ out) {
  const int row = blockIdx.x * 4 + (threadIdx.x >> 6);
  const int lane = threadIdx.x & 63;
  const size_t gb = (size_t)row * 2048 + lane * 8;
  ushort8 sr = *(const ushort8*)&gg[gb];
  ushort8 szv = *(const ushort8*)&gg[gb + 512];
  ushort8 inn = *(const ushort8*)&gg[gb + 1024];
  ushort8 hnn = *(const ushort8*)&gg[gb + 1536];
  float4 t0 = *(const float4*)&team[(size_t)row * 512 + lane * 8];
  float4 t1 = *(const float4*)&team[(size_t)row * 512 + lane * 8 + 4];
  const float im = imp[row];
  float tv[8] = {t0.x, t0.y, t0.z, t0.w, t1.x, t1.y, t1.z, t1.w};
  float u[8];
  float s = 0.f, ss = 0.f;
#pragma unroll
  for (int e = 0; e < 8; ++e) {
    const float rg = sigmoidf_(bf2f(sr[e]));
    const float zg = sigmoidf_(bf2f(szv[e]));
    const float ng = tanhf(bf2f(inn[e]) + rg * bf2f(hnn[e]));
    const float ne = (1.f - zg) * ng + zg * tv[e];
    const float uu = tv[e] + im * (ne - tv[e]);
    u[e] = uu; s += uu; ss += uu * uu;
  }
#pragma unroll
  for (int off = 32; off; off >>= 1) {
    s += __shfl_down(s, off);
    ss += __shfl_down(ss, off);
  }
  s = __shfl(s, 0); ss = __shfl(ss, 0);
  const float mu = s * (1.f / 512.f);
  const float inv = rsqrtf(ss * (1.f / 512.f) - mu * mu + 1e-5f);
  float4 g0 = *(const float4*)&gamma[lane * 8], g1 = *(const float4*)&gamma[lane * 8 + 4];
  float4 b0 = *(const float4*)&beta[lane * 8], b1 = *(const float4*)&beta[lane * 8 + 4];
  float gv[8] = {g0.x, g0.y, g0.z, g0.w, g1.x, g1.y, g1.z, g1.w};
  float bv[8] = {b0.x, b0.y, b0.z, b0.w, b1.x, b1.y, b1.z, b1.w};
  float4 o0, o1;
  o0.x = gv[0] * (u[0] - mu) * inv + bv[0];
  o0.y = gv[1] * (u[1] - mu) * inv + bv[1];
  o0.z = gv[2] * (u[2] - mu) * inv + bv[2];
  o0.w = gv[3] * (u[3] - mu) * inv + bv[3];
  o1.x = gv[4] * (u[4] - mu) * inv + bv[4];
  o1.y = gv[5] * (u[5] - mu) * inv + bv[5];
  o1.z = gv[6] * (u[6] - mu) * inv + bv[6];
  o1.w = gv[7] * (u[7] - mu) * inv + bv[7];
  *(float4*)&out[(size_t)row * 512 + lane * 8] = o0;
  *(float4*)&out[(size_t)row * 512 + lane * 8 + 4] = o1;
}

// ---------------- launch ----------------
extern "C" void kernel_launch(void* const* d_in, const int* in_sizes, int n_in,
                              void* d_out, int out_size, void* d_ws, size_t ws_size,
                              hipStream_t stream) {
  const float* team   = (const float*)d_in[0];
  const float* opp    = (const float*)d_in[1];
  const float* gf     = (const float*)d_in[2];
  const float* won    = (const float*)d_in[3];
  const float* W_proj = (const float*)d_in[4];
  const float* b_proj = (const float*)d_in[5];
  const float* W_ih   = (const float*)d_in[6];
  const float* b_ih   = (const float*)d_in[7];
  const float* W_hh   = (const float*)d_in[8];
  const float* b_hh   = (const float*)d_in[9];
  const float* gamma  = (const float*)d_in[10];
  const float* beta   = (const float*)d_in[11];
  const float* W_imp1 = (const float*)d_in[12];
  const float* b_imp1 = (const float*)d_in[13];
  const float* W_imp2 = (const float*)d_in[14];
  const float* b_imp2 = (const float*)d_in[15];

  char* ws = (char*)d_ws;
  size_t o = 0;
  __hip_bfloat16* Xbf    = (__hip_bfloat16*)(ws + o); o += (size_t)NB * GINP * 2;
  __hip_bfloat16* Wpb    = (__hip_bfloat16*)(ws + o); o += (size_t)512 * GINP * 2;
  __hip_bfloat16* Wrz    = (__hip_bfloat16*)(ws + o); o += (size_t)1024 * 1024 * 2;
  __hip_bfloat16* Wn     = (__hip_bfloat16*)(ws + o); o += (size_t)1024 * 512 * 2;
  __hip_bfloat16* Wimp1b = (__hip_bfloat16*)(ws + o); o += (size_t)128 * 512 * 2;
  float*          bcat   = (float*)(ws + o);          o += (size_t)2048 * 4;
  __hip_bfloat16* Pbf    = (__hip_bfloat16*)(ws + o); o += (size_t)NB * 512 * 2;
  float*          imp    = (float*)(ws + o);          o += (size_t)NB * 4;
  __hip_bfloat16* gg     = (__hip_bfloat16*)(ws + o); o += (size_t)NB * 2048 * 2;

  float* out_updated = (float*)d_out;
  float* out_ctx     = (float*)d_out + (size_t)NB * 512;

  {
    const long wtotal = 512L * 1088 + 1024L * 1024 + 1024L * 512 + 128L * 512 + 2048;
    const int wblocks = (int)((wtotal + 255) / 256);
    prep_all<<<PREP_X_BLOCKS + wblocks, 256, 0, stream>>>(
        team, opp, gf, won, W_proj, W_ih, W_hh, W_imp1, b_ih, b_hh,
        Xbf, Wpb, Wrz, Wn, Wimp1b, bcat);
  }
  // projected = relu(X @ Wpb^T + b_proj): M=16384, N=512, K=1088 -> 128x4 = 512 blocks
  gemm_proj<<<512, 256, 0, stream>>>(Xbf, Wpb, b_proj, out_ctx, Pbf);
  // gates (2048 blocks) + importance (256 tail blocks) in one launch
  gates_imp<<<2304, 256, 0, stream>>>(Pbf, Xbf, Wrz, Wn, bcat, gg,
                                      Wimp1b, b_imp1, W_imp2, b_imp2, imp);
  fuse_final2<<<NB / 4, 256, 0, stream>>>(team, gg, imp, gamma, beta, out_updated);
}